// Round 6
// baseline (421.656 us; speedup 1.0000x reference)
//
#include <hip/hip_runtime.h>

// Problem dims (fixed by the reference): B=256, T=100, D=1024, H=128, C=5
constexpr int Bsz = 256;
constexpr int Tn  = 100;
constexpr int Dn  = 1024;
constexpr int Hn  = 128;
constexpr int Cn  = 5;

// float64 values of np.exp(-1/10), np.exp(-1/20)
#define D1 0.9048374180359595731642491
#define D2 0.9512294245007140090914253

typedef double double4_t __attribute__((ext_vector_type(4)));

// ---------------------------------------------------------------------------
// W1 f32 -> f64 into workspace (1024*128 = 131072 elements)
// ---------------------------------------------------------------------------
__global__ __launch_bounds__(256) void cvt_w1(const float* __restrict__ W1,
                                              double* __restrict__ W1d)
{
  const int i = (blockIdx.x * 256 + threadIdx.x) * 4;
  float4 v = *(const float4*)(W1 + i);
  double2 a, b;
  a.x = (double)v.x; a.y = (double)v.y;
  b.x = (double)v.z; b.y = (double)v.w;
  *(double2*)(W1d + i)     = a;
  *(double2*)(W1d + i + 2) = b;
}

// ---------------------------------------------------------------------------
// Phase 1 (MFMA f64): Hc[r,128] = X[row(r),1024] @ W1[1024,128]
// Block: 256 thr (4 waves), TILE_M=16, FULL N=128 (X staged once).
// Wave w owns n-tiles {w*16, w*16+64}; K split by quad parity ->
// 4 independent accumulator chains per wave (breaks MFMA RAW serialization;
// f64 MFMA = 128 SIMD-cy issue, dep-latency > issue was the round-5 stall).
// A panel staged f32 in LDS [k][m]; B read from W1d (f64, L2-resident).
// D-fragment layout self-calibrated via probe MFMA (round-5 proven).
// ---------------------------------------------------------------------------
constexpr int TILE_M = 16;
constexpr int KC     = 512;
constexpr int APAD   = 17;

__global__ __launch_bounds__(256) void gemm_mfma_f64(
    const float* __restrict__ X, const double* __restrict__ W1d,
    double* __restrict__ Hc, int t0, int Tc)
{
  __shared__ float As[KC][APAD];      // [k][m], 512*17*4 = 34816 B

  const int tid = threadIdx.x;
  const int m0  = blockIdx.x * TILE_M;

  // staging: thread t -> A row rA=t>>4, float4 column group c4=t&15 (+ j*16)
  const int rA = tid >> 4;
  const int c4 = tid & 15;
  const int rc   = m0 + rA;
  const int bidx = rc / Tc;
  const int tl   = rc - bidx * Tc;
  const int grow = bidx * Tn + t0 + tl;
  const float* Apt = X + (size_t)grow * Dn;

  // compute: wave w -> n-tiles w*16 and w*16+64
  const int w    = tid >> 6;
  const int lane = tid & 63;
  const int mA   = lane & 15;         // A row / B col index supplied
  const int kq   = lane >> 4;         // k index supplied (0..3)
  const int n0   = w * 16;

  // --- D-layout probe: D[i][j] = 16*i + j ------------------------------
  int drow[4], dcol[4];
  {
    const double ap = (kq == 0) ? (double)(16 * mA) : (kq == 1 ? 1.0 : 0.0);
    const double bpv = (kq == 0) ? 1.0 : (kq == 1 ? (double)mA : 0.0);
    double4_t pz = {0.0, 0.0, 0.0, 0.0};
    pz = __builtin_amdgcn_mfma_f64_16x16x4f64(ap, bpv, pz, 0, 0, 0);
    #pragma unroll
    for (int r = 0; r < 4; ++r) {
      const int p = (int)pz[r];
      drow[r] = p >> 4;
      dcol[r] = p & 15;
    }
  }

  double4_t acc0 = {0.0, 0.0, 0.0, 0.0};   // n-tile 0, K parity 0
  double4_t acc1 = {0.0, 0.0, 0.0, 0.0};   // n-tile 1, K parity 0
  double4_t acc2 = {0.0, 0.0, 0.0, 0.0};   // n-tile 0, K parity 1
  double4_t acc3 = {0.0, 0.0, 0.0, 0.0};   // n-tile 1, K parity 1

  for (int kc = 0; kc < Dn; kc += KC) {
    __syncthreads();
    // stage 16 rows x 512 cols f32 into As[k][m]
    #pragma unroll
    for (int j = 0; j < 8; ++j) {
      const int f = c4 + j * 16;              // float4 index within chunk
      float4 v = *(const float4*)(Apt + kc + 4 * f);
      As[4*f + 0][rA] = v.x;
      As[4*f + 1][rA] = v.y;
      As[4*f + 2][rA] = v.z;
      As[4*f + 3][rA] = v.w;
    }
    __syncthreads();

    const double* bp = W1d + (size_t)(kc + kq) * Hn + n0 + mA;
    #pragma unroll 4
    for (int k0 = 0; k0 < KC; k0 += 8) {
      // quad pair: parity-0 quad k0, parity-1 quad k0+4
      const double a0  = (double)As[k0 + kq][mA];
      const double b00 = bp[(size_t)k0 * Hn];
      const double b01 = bp[(size_t)k0 * Hn + 64];
      acc0 = __builtin_amdgcn_mfma_f64_16x16x4f64(a0, b00, acc0, 0, 0, 0);
      acc1 = __builtin_amdgcn_mfma_f64_16x16x4f64(a0, b01, acc1, 0, 0, 0);
      const double a1  = (double)As[k0 + 4 + kq][mA];
      const double b10 = bp[(size_t)(k0 + 4) * Hn];
      const double b11 = bp[(size_t)(k0 + 4) * Hn + 64];
      acc2 = __builtin_amdgcn_mfma_f64_16x16x4f64(a1, b10, acc2, 0, 0, 0);
      acc3 = __builtin_amdgcn_mfma_f64_16x16x4f64(a1, b11, acc3, 0, 0, 0);
    }
  }

  // epilogue via self-calibrated mapping; merge parity chains (f64 add,
  // order-robust: rounds 2/3/5 all bit-exact under different orders)
  #pragma unroll
  for (int r = 0; r < 4; ++r) {
    Hc[(size_t)(m0 + drow[r]) * Hn + n0 + dcol[r]]      = acc0[r] + acc2[r];
    Hc[(size_t)(m0 + drow[r]) * Hn + n0 + 64 + dcol[r]] = acc1[r] + acc3[r];
  }
}

// ---------------------------------------------------------------------------
// Phase 2: per-batch-row LIF scan over t in [t0, t0+Tc), fp64 state in ws.
// One 64-lane wave per batch row; each lane owns 2 hidden neurons.
// ---------------------------------------------------------------------------
__global__ __launch_bounds__(64) void snn_scan_f64(
    const double* __restrict__ Hc, const float* __restrict__ b1,
    const float* __restrict__ W2, const float* __restrict__ b2,
    double* __restrict__ v1s, double* __restrict__ v2s,
    double* __restrict__ accs, float* __restrict__ out, int t0, int Tc)
{
#pragma clang fp contract(off)
  const int b    = blockIdx.x;
  const int lane = threadIdx.x;
  const int j0   = lane * 2;

  double w2a[Cn], w2b[Cn], bb2[Cn];
  #pragma unroll
  for (int c = 0; c < Cn; ++c) {
    w2a[c] = (double)W2[(size_t)j0 * Cn + c];
    w2b[c] = (double)W2[(size_t)(j0 + 1) * Cn + c];
    bb2[c] = (double)b2[c];
  }
  const double b1a = (double)b1[j0];
  const double b1b = (double)b1[j0 + 1];

  double v1a, v1b, v2[Cn], acc[Cn];
  if (t0 == 0) {
    v1a = 0.0; v1b = 0.0;
    #pragma unroll
    for (int c = 0; c < Cn; ++c) { v2[c] = 0.0; acc[c] = 0.0; }
  } else {
    v1a = v1s[(size_t)b * Hn + j0];
    v1b = v1s[(size_t)b * Hn + j0 + 1];
    #pragma unroll
    for (int c = 0; c < Cn; ++c) {
      v2[c]  = v2s[(size_t)b * Cn + c];
      acc[c] = accs[(size_t)b * Cn + c];
    }
  }

  const double* hp = Hc + (size_t)b * Tc * Hn + j0;
  double2 hnext = *(const double2*)hp;

  for (int t = 0; t < Tc; ++t) {
    const double2 hc = hnext;
    const int tn = (t + 1 < Tc) ? (t + 1) : t;
    hnext = *(const double2*)(hp + (size_t)tn * Hn);

    // v1 = (v1*d1 + h) + b1  (left-assoc, separate roundings)
    v1a = (v1a * D1 + hc.x) + b1a;
    v1b = (v1b * D1 + hc.y) + b1b;
    const double s1a = (v1a >= 1.0) ? 1.0 : 0.0;
    const double s1b = (v1b >= 1.0) ? 1.0 : 0.0;
    v1a = (v1a >= 1.0) ? 0.0 : v1a;
    v1b = (v1b >= 1.0) ? 0.0 : v1b;

    // p[c] = sum_j s1[j] * W2[j,c]  (fp64 butterfly)
    double p[Cn];
    #pragma unroll
    for (int c = 0; c < Cn; ++c)
      p[c] = s1a * w2a[c] + s1b * w2b[c];
    #pragma unroll
    for (int off = 32; off > 0; off >>= 1) {
      #pragma unroll
      for (int c = 0; c < Cn; ++c)
        p[c] += __shfl_xor(p[c], off);
    }

    // v2 = ((v2*d2) + p) + b2
    #pragma unroll
    for (int c = 0; c < Cn; ++c) {
      const double v = ((v2[c] * D2) + p[c]) + bb2[c];
      const double s2 = (v >= 1.0) ? 1.0 : 0.0;
      v2[c]  = (v >= 1.0) ? 0.0 : v;
      acc[c] += s2;
    }
  }

  // persist state for next chunk
  v1s[(size_t)b * Hn + j0]     = v1a;
  v1s[(size_t)b * Hn + j0 + 1] = v1b;
  if (lane == 0) {
    #pragma unroll
    for (int c = 0; c < Cn; ++c) {
      v2s[(size_t)b * Cn + c]  = v2[c];
      accs[(size_t)b * Cn + c] = acc[c];
    }
    if (t0 + Tc == Tn) {
      #pragma unroll
      for (int c = 0; c < Cn; ++c)
        out[(size_t)b * Cn + c] = (float)(acc[c] / 100.0);
    }
  }
}

// ---------------------------------------------------------------------------
extern "C" void kernel_launch(void* const* d_in, const int* in_sizes, int n_in,
                              void* d_out, int out_size, void* d_ws, size_t ws_size,
                              hipStream_t stream) {
  const float* X  = (const float*)d_in[0];   // [B,T,D]
  const float* W1 = (const float*)d_in[1];   // [D,H]
  const float* b1 = (const float*)d_in[2];   // [H]
  const float* W2 = (const float*)d_in[3];   // [H,C]
  const float* b2 = (const float*)d_in[4];   // [C]
  float* out = (float*)d_out;                // [B,C]

  // ws layout: W1d (1 MB) | Hc [B*Tc,H] | v1s | v2s | accs   (all f64)
  const size_t w1Doubles    = (size_t)Dn * Hn;                    // 131072
  const size_t stateDoubles = (size_t)Bsz * Hn + 2 * (size_t)Bsz * Cn;
  static const int cands[] = {100, 50, 25, 20, 10, 5, 4, 2, 1};
  int Tc = 1;
  for (int i = 0; i < 9; ++i) {
    const size_t need =
        (w1Doubles + (size_t)Bsz * cands[i] * Hn + stateDoubles) * sizeof(double);
    if (need <= ws_size) { Tc = cands[i]; break; }
  }

  double* W1d  = (double*)d_ws;
  double* Hc   = W1d + w1Doubles;                    // [B*Tc, H]
  double* v1s  = Hc  + (size_t)Bsz * Tc * Hn;        // [B, H]
  double* v2s  = v1s + (size_t)Bsz * Hn;             // [B, C]
  double* accs = v2s + (size_t)Bsz * Cn;             // [B, C]

  cvt_w1<<<dim3((Dn * Hn) / (256 * 4)), dim3(256), 0, stream>>>(W1, W1d);

  for (int t0 = 0; t0 < Tn; t0 += Tc) {
    const int rows = Bsz * Tc;
    gemm_mfma_f64<<<dim3(rows / TILE_M), dim3(256), 0, stream>>>(
        X, W1d, Hc, t0, Tc);
    snn_scan_f64<<<dim3(Bsz), dim3(64), 0, stream>>>(Hc, b1, W2, b2,
                                                     v1s, v2s, accs, out, t0, Tc);
  }
}

// Round 7
// 410.056 us; speedup vs baseline: 1.0283x; 1.0283x over previous
//
#include <hip/hip_runtime.h>

// Problem dims (fixed by the reference): B=256, T=100, D=1024, H=128, C=5
constexpr int Bsz = 256;
constexpr int Tn  = 100;
constexpr int Dn  = 1024;
constexpr int Hn  = 128;
constexpr int Cn  = 5;

// float64 values of np.exp(-1/10), np.exp(-1/20)
#define D1 0.9048374180359595731642491
#define D2 0.9512294245007140090914253

typedef double double4_t __attribute__((ext_vector_type(4)));

// ---------------------------------------------------------------------------
// W1 f32 -> f64 into workspace (1024*128 = 131072 elements)
// ---------------------------------------------------------------------------
__global__ __launch_bounds__(256) void cvt_w1(const float* __restrict__ W1,
                                              double* __restrict__ W1d)
{
  const int i = (blockIdx.x * 256 + threadIdx.x) * 4;
  float4 v = *(const float4*)(W1 + i);
  double2 a, b;
  a.x = (double)v.x; a.y = (double)v.y;
  b.x = (double)v.z; b.y = (double)v.w;
  *(double2*)(W1d + i)     = a;
  *(double2*)(W1d + i + 2) = b;
}

// ---------------------------------------------------------------------------
// Phase 1 (MFMA f64): Hc[r,128] += X[row(r), kh*512 : kh*512+512] @ W1d[...]
// K-split x2: grid = 2 * rows/16 blocks (kh = blockIdx&1) -> 1600 blocks
// per dispatch = 6.25/CU (balance 0.89 vs round-6's 0.78). Outputs merged
// with HW f64 atomic add (2 addends commute bit-exactly; Hc pre-zeroed).
// Staging: 4 sub-chunks of 128 k, double-buffered LDS (2 x 8.7 KB), one
// barrier per sub-chunk -> staging overlaps MFMA (round-6's 20% dead time).
// Wave w owns n-tiles {w*16, w*16+64}; 2 K-parity chains per tile.
// D-fragment layout self-calibrated via probe MFMA (round-5 proven).
// ---------------------------------------------------------------------------
constexpr int TILE_M = 16;
constexpr int KH     = 512;           // K half per block
constexpr int SC     = 128;           // staging sub-chunk
constexpr int NS     = KH / SC;       // 4
constexpr int APAD   = 17;

__global__ __launch_bounds__(256) void gemm_mfma_f64(
    const float* __restrict__ X, const double* __restrict__ W1d,
    double* __restrict__ Hc, int t0, int Tc)
{
  __shared__ float As[2][SC][APAD];   // 2 * 128*17*4 = 17408 B

  const int tid   = threadIdx.x;
  const int mt    = blockIdx.x >> 1;
  const int kh    = blockIdx.x & 1;
  const int m0    = mt * TILE_M;
  const int kbase = kh * KH;

  // staging: thread t -> A row rA=t>>4, float4 groups c4 and c4+16
  const int rA = tid >> 4;
  const int c4 = tid & 15;
  const int rc   = m0 + rA;
  const int bidx = rc / Tc;
  const int tl   = rc - bidx * Tc;
  const int grow = bidx * Tn + t0 + tl;
  const float* Apt = X + (size_t)grow * Dn + kbase;

  // compute: wave w -> n-tiles w*16 and w*16+64
  const int w    = tid >> 6;
  const int lane = tid & 63;
  const int mA   = lane & 15;         // A row / B col index supplied
  const int kq   = lane >> 4;         // k index supplied (0..3)
  const int n0   = w * 16;

  // --- D-layout probe: D[i][j] = 16*i + j ------------------------------
  int drow[4], dcol[4];
  {
    const double ap  = (kq == 0) ? (double)(16 * mA) : (kq == 1 ? 1.0 : 0.0);
    const double bpv = (kq == 0) ? 1.0 : (kq == 1 ? (double)mA : 0.0);
    double4_t pz = {0.0, 0.0, 0.0, 0.0};
    pz = __builtin_amdgcn_mfma_f64_16x16x4f64(ap, bpv, pz, 0, 0, 0);
    #pragma unroll
    for (int r = 0; r < 4; ++r) {
      const int p = (int)pz[r];
      drow[r] = p >> 4;
      dcol[r] = p & 15;
    }
  }

  double4_t acc0 = {0.0, 0.0, 0.0, 0.0};   // n-tile 0, K parity 0
  double4_t acc1 = {0.0, 0.0, 0.0, 0.0};   // n-tile 1, K parity 0
  double4_t acc2 = {0.0, 0.0, 0.0, 0.0};   // n-tile 0, K parity 1
  double4_t acc3 = {0.0, 0.0, 0.0, 0.0};   // n-tile 1, K parity 1

  // prefetch sub-chunk 0
  float4 p0 = *(const float4*)(Apt + 4 * c4);
  float4 p1 = *(const float4*)(Apt + 4 * (c4 + 16));

  int buf = 0;
  for (int s = 0; s < NS; ++s) {
    // write staged registers into LDS buffer `buf`
    {
      const int f0 = 4 * c4, f1 = 4 * (c4 + 16);
      As[buf][f0 + 0][rA] = p0.x;
      As[buf][f0 + 1][rA] = p0.y;
      As[buf][f0 + 2][rA] = p0.z;
      As[buf][f0 + 3][rA] = p0.w;
      As[buf][f1 + 0][rA] = p1.x;
      As[buf][f1 + 1][rA] = p1.y;
      As[buf][f1 + 2][rA] = p1.z;
      As[buf][f1 + 3][rA] = p1.w;
    }
    __syncthreads();

    // prefetch sub-chunk s+1 (global loads overlap compute below)
    if (s + 1 < NS) {
      p0 = *(const float4*)(Apt + (s + 1) * SC + 4 * c4);
      p1 = *(const float4*)(Apt + (s + 1) * SC + 4 * (c4 + 16));
    }

    const double* bp = W1d + (size_t)(kbase + s * SC + kq) * Hn + n0 + mA;
    #pragma unroll 4
    for (int k0 = 0; k0 < SC; k0 += 8) {
      const double a0  = (double)As[buf][k0 + kq][mA];
      const double b00 = bp[(size_t)k0 * Hn];
      const double b01 = bp[(size_t)k0 * Hn + 64];
      acc0 = __builtin_amdgcn_mfma_f64_16x16x4f64(a0, b00, acc0, 0, 0, 0);
      acc1 = __builtin_amdgcn_mfma_f64_16x16x4f64(a0, b01, acc1, 0, 0, 0);
      const double a1  = (double)As[buf][k0 + 4 + kq][mA];
      const double b10 = bp[(size_t)(k0 + 4) * Hn];
      const double b11 = bp[(size_t)(k0 + 4) * Hn + 64];
      acc2 = __builtin_amdgcn_mfma_f64_16x16x4f64(a1, b10, acc2, 0, 0, 0);
      acc3 = __builtin_amdgcn_mfma_f64_16x16x4f64(a1, b11, acc3, 0, 0, 0);
    }
    buf ^= 1;
  }

  // epilogue: merge parity chains locally, atomic-add across the 2 K-halves
  // (two commuting f64 adds onto 0 -> bit-exact regardless of arrival order)
  #pragma unroll
  for (int r = 0; r < 4; ++r) {
    double* e0 = &Hc[(size_t)(m0 + drow[r]) * Hn + n0 + dcol[r]];
    double* e1 = &Hc[(size_t)(m0 + drow[r]) * Hn + n0 + 64 + dcol[r]];
    __hip_atomic_fetch_add(e0, acc0[r] + acc2[r],
                           __ATOMIC_RELAXED, __HIP_MEMORY_SCOPE_AGENT);
    __hip_atomic_fetch_add(e1, acc1[r] + acc3[r],
                           __ATOMIC_RELAXED, __HIP_MEMORY_SCOPE_AGENT);
  }
}

// ---------------------------------------------------------------------------
// Phase 2: per-batch-row LIF scan over t in [t0, t0+Tc), fp64 state in ws.
// One 64-lane wave per batch row; each lane owns 2 hidden neurons.
// ---------------------------------------------------------------------------
__global__ __launch_bounds__(64) void snn_scan_f64(
    const double* __restrict__ Hc, const float* __restrict__ b1,
    const float* __restrict__ W2, const float* __restrict__ b2,
    double* __restrict__ v1s, double* __restrict__ v2s,
    double* __restrict__ accs, float* __restrict__ out, int t0, int Tc)
{
#pragma clang fp contract(off)
  const int b    = blockIdx.x;
  const int lane = threadIdx.x;
  const int j0   = lane * 2;

  double w2a[Cn], w2b[Cn], bb2[Cn];
  #pragma unroll
  for (int c = 0; c < Cn; ++c) {
    w2a[c] = (double)W2[(size_t)j0 * Cn + c];
    w2b[c] = (double)W2[(size_t)(j0 + 1) * Cn + c];
    bb2[c] = (double)b2[c];
  }
  const double b1a = (double)b1[j0];
  const double b1b = (double)b1[j0 + 1];

  double v1a, v1b, v2[Cn], acc[Cn];
  if (t0 == 0) {
    v1a = 0.0; v1b = 0.0;
    #pragma unroll
    for (int c = 0; c < Cn; ++c) { v2[c] = 0.0; acc[c] = 0.0; }
  } else {
    v1a = v1s[(size_t)b * Hn + j0];
    v1b = v1s[(size_t)b * Hn + j0 + 1];
    #pragma unroll
    for (int c = 0; c < Cn; ++c) {
      v2[c]  = v2s[(size_t)b * Cn + c];
      acc[c] = accs[(size_t)b * Cn + c];
    }
  }

  const double* hp = Hc + (size_t)b * Tc * Hn + j0;
  double2 hnext = *(const double2*)hp;

  for (int t = 0; t < Tc; ++t) {
    const double2 hc = hnext;
    const int tn = (t + 1 < Tc) ? (t + 1) : t;
    hnext = *(const double2*)(hp + (size_t)tn * Hn);

    // v1 = (v1*d1 + h) + b1  (left-assoc, separate roundings)
    v1a = (v1a * D1 + hc.x) + b1a;
    v1b = (v1b * D1 + hc.y) + b1b;
    const double s1a = (v1a >= 1.0) ? 1.0 : 0.0;
    const double s1b = (v1b >= 1.0) ? 1.0 : 0.0;
    v1a = (v1a >= 1.0) ? 0.0 : v1a;
    v1b = (v1b >= 1.0) ? 0.0 : v1b;

    // p[c] = sum_j s1[j] * W2[j,c]  (fp64 butterfly)
    double p[Cn];
    #pragma unroll
    for (int c = 0; c < Cn; ++c)
      p[c] = s1a * w2a[c] + s1b * w2b[c];
    #pragma unroll
    for (int off = 32; off > 0; off >>= 1) {
      #pragma unroll
      for (int c = 0; c < Cn; ++c)
        p[c] += __shfl_xor(p[c], off);
    }

    // v2 = ((v2*d2) + p) + b2
    #pragma unroll
    for (int c = 0; c < Cn; ++c) {
      const double v = ((v2[c] * D2) + p[c]) + bb2[c];
      const double s2 = (v >= 1.0) ? 1.0 : 0.0;
      v2[c]  = (v >= 1.0) ? 0.0 : v;
      acc[c] += s2;
    }
  }

  // persist state for next chunk
  v1s[(size_t)b * Hn + j0]     = v1a;
  v1s[(size_t)b * Hn + j0 + 1] = v1b;
  if (lane == 0) {
    #pragma unroll
    for (int c = 0; c < Cn; ++c) {
      v2s[(size_t)b * Cn + c]  = v2[c];
      accs[(size_t)b * Cn + c] = acc[c];
    }
    if (t0 + Tc == Tn) {
      #pragma unroll
      for (int c = 0; c < Cn; ++c)
        out[(size_t)b * Cn + c] = (float)(acc[c] / 100.0);
    }
  }
}

// ---------------------------------------------------------------------------
extern "C" void kernel_launch(void* const* d_in, const int* in_sizes, int n_in,
                              void* d_out, int out_size, void* d_ws, size_t ws_size,
                              hipStream_t stream) {
  const float* X  = (const float*)d_in[0];   // [B,T,D]
  const float* W1 = (const float*)d_in[1];   // [D,H]
  const float* b1 = (const float*)d_in[2];   // [H]
  const float* W2 = (const float*)d_in[3];   // [H,C]
  const float* b2 = (const float*)d_in[4];   // [C]
  float* out = (float*)d_out;                // [B,C]

  // ws layout: W1d (1 MB) | Hc [B*Tc,H] | v1s | v2s | accs   (all f64)
  const size_t w1Doubles    = (size_t)Dn * Hn;                    // 131072
  const size_t stateDoubles = (size_t)Bsz * Hn + 2 * (size_t)Bsz * Cn;
  static const int cands[] = {100, 50, 25, 20, 10, 5, 4, 2, 1};
  int Tc = 1;
  for (int i = 0; i < 9; ++i) {
    const size_t need =
        (w1Doubles + (size_t)Bsz * cands[i] * Hn + stateDoubles) * sizeof(double);
    if (need <= ws_size) { Tc = cands[i]; break; }
  }

  double* W1d  = (double*)d_ws;
  double* Hc   = W1d + w1Doubles;                    // [B*Tc, H]
  double* v1s  = Hc  + (size_t)Bsz * Tc * Hn;        // [B, H]
  double* v2s  = v1s + (size_t)Bsz * Hn;             // [B, C]
  double* accs = v2s + (size_t)Bsz * Cn;             // [B, C]
  const size_t hcBytes = (size_t)Bsz * Tc * Hn * sizeof(double);

  cvt_w1<<<dim3((Dn * Hn) / (256 * 4)), dim3(256), 0, stream>>>(W1, W1d);

  for (int t0 = 0; t0 < Tn; t0 += Tc) {
    const int rows = Bsz * Tc;
    hipMemsetAsync(Hc, 0, hcBytes, stream);          // atomic accumulation base
    gemm_mfma_f64<<<dim3((rows / TILE_M) * 2), dim3(256), 0, stream>>>(
        X, W1d, Hc, t0, Tc);
    snn_scan_f64<<<dim3(Bsz), dim3(64), 0, stream>>>(Hc, b1, W2, b2,
                                                     v1s, v2s, accs, out, t0, Tc);
  }
}

// Round 8
// 403.661 us; speedup vs baseline: 1.0446x; 1.0158x over previous
//
#include <hip/hip_runtime.h>

// Problem dims (fixed by the reference): B=256, T=100, D=1024, H=128, C=5
constexpr int Bsz = 256;
constexpr int Tn  = 100;
constexpr int Dn  = 1024;
constexpr int Hn  = 128;
constexpr int Cn  = 5;

// float64 values of np.exp(-1/10), np.exp(-1/20)
#define D1 0.9048374180359595731642491
#define D2 0.9512294245007140090914253

typedef double double4_t __attribute__((ext_vector_type(4)));

// ---------------------------------------------------------------------------
// W1 f32 -> f64 into workspace (1024*128 = 131072 elements)
// ---------------------------------------------------------------------------
__global__ __launch_bounds__(256) void cvt_w1(const float* __restrict__ W1,
                                              double* __restrict__ W1d)
{
  const int i = (blockIdx.x * 256 + threadIdx.x) * 4;
  float4 v = *(const float4*)(W1 + i);
  double2 a, b;
  a.x = (double)v.x; a.y = (double)v.y;
  b.x = (double)v.z; b.y = (double)v.w;
  *(double2*)(W1d + i)     = a;
  *(double2*)(W1d + i + 2) = b;
}

// ---------------------------------------------------------------------------
// Phase 1 (MFMA f64): Hc[r,128] += X[rows, kq*256:+256] @ W1d[slice]
// Measured: v_mfma_f64_16x16x4 ceiling ~38 TF (128 cy/instr); rounds 5-7
// stuck at ~55% util -> B-load (L2) wait-bound. Fix: TILE_M=32 -> each wave
// does 4 MFMA (2 m-subtiles x 2 n-tiles) per k-quad sharing 2 A + 2 B loads:
// per-MFMA B-load rate halves. K-split x4 keeps grid at 1600 (6.25/CU).
// Output merged via f64 atomic add onto memset-zeroed Hc.
// D-fragment layout self-calibrated via probe MFMA (round-5 proven).
// ---------------------------------------------------------------------------
constexpr int TILE_M = 32;
constexpr int KSPL   = 4;
constexpr int KH     = Dn / KSPL;     // 256 k per block
constexpr int SC     = 128;           // staging sub-chunk (k)
constexpr int NS     = KH / SC;       // 2
constexpr int APAD   = 33;            // 32 m + 1 pad (f32)

__global__ __launch_bounds__(256) void gemm_mfma_f64(
    const float* __restrict__ X, const double* __restrict__ W1d,
    double* __restrict__ Hc, int t0, int Tc)
{
  __shared__ float As[2][SC][APAD];   // 2 * 128*33*4 = 33792 B

  const int tid   = threadIdx.x;
  const int mt    = blockIdx.x >> 2;
  const int kspl  = blockIdx.x & 3;
  const int m0    = mt * TILE_M;
  const int kbase = kspl * KH;

  // staging: thread t -> A row rA=t>>3 (0..31), float4 k-group c8=t&7 (+ j*8)
  const int rA = tid >> 3;
  const int c8 = tid & 7;
  const int rc   = m0 + rA;
  const int bidx = rc / Tc;
  const int tl   = rc - bidx * Tc;
  const int grow = bidx * Tn + t0 + tl;
  const float* Apt = X + (size_t)grow * Dn + kbase;

  // compute: wave w -> n-tiles {w*16, w*16+64}, m-subtiles {0,16}
  const int w    = tid >> 6;
  const int lane = tid & 63;
  const int mA   = lane & 15;         // A row / B col index supplied
  const int kq   = lane >> 4;         // k index supplied (0..3)
  const int n0   = w * 16;

  // --- D-layout probe: D[i][j] = 16*i + j ------------------------------
  int drow[4], dcol[4];
  {
    const double ap  = (kq == 0) ? (double)(16 * mA) : (kq == 1 ? 1.0 : 0.0);
    const double bpv = (kq == 0) ? 1.0 : (kq == 1 ? (double)mA : 0.0);
    double4_t pz = {0.0, 0.0, 0.0, 0.0};
    pz = __builtin_amdgcn_mfma_f64_16x16x4f64(ap, bpv, pz, 0, 0, 0);
    #pragma unroll
    for (int r = 0; r < 4; ++r) {
      const int p = (int)pz[r];
      drow[r] = p >> 4;
      dcol[r] = p & 15;
    }
  }

  double4_t acc00 = {0.0, 0.0, 0.0, 0.0};  // m-sub 0, n-tile 0
  double4_t acc01 = {0.0, 0.0, 0.0, 0.0};  // m-sub 0, n-tile 1
  double4_t acc10 = {0.0, 0.0, 0.0, 0.0};  // m-sub 1, n-tile 0
  double4_t acc11 = {0.0, 0.0, 0.0, 0.0};  // m-sub 1, n-tile 1

  // prefetch sub-chunk 0: 4 float4 per thread (32 m x 128 k / 256 thr)
  float4 pf[4];
  #pragma unroll
  for (int j = 0; j < 4; ++j)
    pf[j] = *(const float4*)(Apt + 4 * (c8 + j * 8));

  int buf = 0;
  for (int s = 0; s < NS; ++s) {
    // write staged registers into LDS buffer `buf` (As[k][m] layout)
    #pragma unroll
    for (int j = 0; j < 4; ++j) {
      const int f = 4 * (c8 + j * 8);
      As[buf][f + 0][rA] = pf[j].x;
      As[buf][f + 1][rA] = pf[j].y;
      As[buf][f + 2][rA] = pf[j].z;
      As[buf][f + 3][rA] = pf[j].w;
    }
    __syncthreads();

    // prefetch sub-chunk s+1 (overlaps compute below)
    if (s + 1 < NS) {
      #pragma unroll
      for (int j = 0; j < 4; ++j)
        pf[j] = *(const float4*)(Apt + (s + 1) * SC + 4 * (c8 + j * 8));
    }

    const double* bp = W1d + (size_t)(kbase + s * SC + kq) * Hn + n0 + mA;
    #pragma unroll 4
    for (int k0 = 0; k0 < SC; k0 += 4) {
      const double a0 = (double)As[buf][k0 + kq][mA];        // m-sub 0
      const double a1 = (double)As[buf][k0 + kq][16 + mA];   // m-sub 1
      const double b0 = bp[(size_t)k0 * Hn];                 // n-tile 0
      const double b1 = bp[(size_t)k0 * Hn + 64];            // n-tile 1
      acc00 = __builtin_amdgcn_mfma_f64_16x16x4f64(a0, b0, acc00, 0, 0, 0);
      acc01 = __builtin_amdgcn_mfma_f64_16x16x4f64(a0, b1, acc01, 0, 0, 0);
      acc10 = __builtin_amdgcn_mfma_f64_16x16x4f64(a1, b0, acc10, 0, 0, 0);
      acc11 = __builtin_amdgcn_mfma_f64_16x16x4f64(a1, b1, acc11, 0, 0, 0);
    }
    buf ^= 1;
  }

  // epilogue: atomic-add partial K-quarter into Hc (memset-zeroed base)
  #pragma unroll
  for (int r = 0; r < 4; ++r) {
    double* e00 = &Hc[(size_t)(m0 + drow[r]) * Hn + n0 + dcol[r]];
    double* e01 = &Hc[(size_t)(m0 + drow[r]) * Hn + n0 + 64 + dcol[r]];
    double* e10 = &Hc[(size_t)(m0 + 16 + drow[r]) * Hn + n0 + dcol[r]];
    double* e11 = &Hc[(size_t)(m0 + 16 + drow[r]) * Hn + n0 + 64 + dcol[r]];
    __hip_atomic_fetch_add(e00, acc00[r], __ATOMIC_RELAXED, __HIP_MEMORY_SCOPE_AGENT);
    __hip_atomic_fetch_add(e01, acc01[r], __ATOMIC_RELAXED, __HIP_MEMORY_SCOPE_AGENT);
    __hip_atomic_fetch_add(e10, acc10[r], __ATOMIC_RELAXED, __HIP_MEMORY_SCOPE_AGENT);
    __hip_atomic_fetch_add(e11, acc11[r], __ATOMIC_RELAXED, __HIP_MEMORY_SCOPE_AGENT);
  }
}

// ---------------------------------------------------------------------------
// Phase 2: per-batch-row LIF scan over t in [t0, t0+Tc), fp64 state in ws.
// One 64-lane wave per batch row; each lane owns 2 hidden neurons.
// ---------------------------------------------------------------------------
__global__ __launch_bounds__(64) void snn_scan_f64(
    const double* __restrict__ Hc, const float* __restrict__ b1,
    const float* __restrict__ W2, const float* __restrict__ b2,
    double* __restrict__ v1s, double* __restrict__ v2s,
    double* __restrict__ accs, float* __restrict__ out, int t0, int Tc)
{
#pragma clang fp contract(off)
  const int b    = blockIdx.x;
  const int lane = threadIdx.x;
  const int j0   = lane * 2;

  double w2a[Cn], w2b[Cn], bb2[Cn];
  #pragma unroll
  for (int c = 0; c < Cn; ++c) {
    w2a[c] = (double)W2[(size_t)j0 * Cn + c];
    w2b[c] = (double)W2[(size_t)(j0 + 1) * Cn + c];
    bb2[c] = (double)b2[c];
  }
  const double b1a = (double)b1[j0];
  const double b1b = (double)b1[j0 + 1];

  double v1a, v1b, v2[Cn], acc[Cn];
  if (t0 == 0) {
    v1a = 0.0; v1b = 0.0;
    #pragma unroll
    for (int c = 0; c < Cn; ++c) { v2[c] = 0.0; acc[c] = 0.0; }
  } else {
    v1a = v1s[(size_t)b * Hn + j0];
    v1b = v1s[(size_t)b * Hn + j0 + 1];
    #pragma unroll
    for (int c = 0; c < Cn; ++c) {
      v2[c]  = v2s[(size_t)b * Cn + c];
      acc[c] = accs[(size_t)b * Cn + c];
    }
  }

  const double* hp = Hc + (size_t)b * Tc * Hn + j0;
  double2 hnext = *(const double2*)hp;

  for (int t = 0; t < Tc; ++t) {
    const double2 hc = hnext;
    const int tn = (t + 1 < Tc) ? (t + 1) : t;
    hnext = *(const double2*)(hp + (size_t)tn * Hn);

    // v1 = (v1*d1 + h) + b1  (left-assoc, separate roundings)
    v1a = (v1a * D1 + hc.x) + b1a;
    v1b = (v1b * D1 + hc.y) + b1b;
    const double s1a = (v1a >= 1.0) ? 1.0 : 0.0;
    const double s1b = (v1b >= 1.0) ? 1.0 : 0.0;
    v1a = (v1a >= 1.0) ? 0.0 : v1a;
    v1b = (v1b >= 1.0) ? 0.0 : v1b;

    // p[c] = sum_j s1[j] * W2[j,c]  (fp64 butterfly)
    double p[Cn];
    #pragma unroll
    for (int c = 0; c < Cn; ++c)
      p[c] = s1a * w2a[c] + s1b * w2b[c];
    #pragma unroll
    for (int off = 32; off > 0; off >>= 1) {
      #pragma unroll
      for (int c = 0; c < Cn; ++c)
        p[c] += __shfl_xor(p[c], off);
    }

    // v2 = ((v2*d2) + p) + b2
    #pragma unroll
    for (int c = 0; c < Cn; ++c) {
      const double v = ((v2[c] * D2) + p[c]) + bb2[c];
      const double s2 = (v >= 1.0) ? 1.0 : 0.0;
      v2[c]  = (v >= 1.0) ? 0.0 : v;
      acc[c] += s2;
    }
  }

  // persist state for next chunk
  v1s[(size_t)b * Hn + j0]     = v1a;
  v1s[(size_t)b * Hn + j0 + 1] = v1b;
  if (lane == 0) {
    #pragma unroll
    for (int c = 0; c < Cn; ++c) {
      v2s[(size_t)b * Cn + c]  = v2[c];
      accs[(size_t)b * Cn + c] = acc[c];
    }
    if (t0 + Tc == Tn) {
      #pragma unroll
      for (int c = 0; c < Cn; ++c)
        out[(size_t)b * Cn + c] = (float)(acc[c] / 100.0);
    }
  }
}

// ---------------------------------------------------------------------------
extern "C" void kernel_launch(void* const* d_in, const int* in_sizes, int n_in,
                              void* d_out, int out_size, void* d_ws, size_t ws_size,
                              hipStream_t stream) {
  const float* X  = (const float*)d_in[0];   // [B,T,D]
  const float* W1 = (const float*)d_in[1];   // [D,H]
  const float* b1 = (const float*)d_in[2];   // [H]
  const float* W2 = (const float*)d_in[3];   // [H,C]
  const float* b2 = (const float*)d_in[4];   // [C]
  float* out = (float*)d_out;                // [B,C]

  // ws layout: W1d (1 MB) | Hc [B*Tc,H] | v1s | v2s | accs   (all f64)
  const size_t w1Doubles    = (size_t)Dn * Hn;                    // 131072
  const size_t stateDoubles = (size_t)Bsz * Hn + 2 * (size_t)Bsz * Cn;
  static const int cands[] = {100, 50, 25, 20, 10, 5, 4, 2, 1};
  int Tc = 1;
  for (int i = 0; i < 9; ++i) {
    const size_t need =
        (w1Doubles + (size_t)Bsz * cands[i] * Hn + stateDoubles) * sizeof(double);
    if (need <= ws_size) { Tc = cands[i]; break; }
  }

  double* W1d  = (double*)d_ws;
  double* Hc   = W1d + w1Doubles;                    // [B*Tc, H]
  double* v1s  = Hc  + (size_t)Bsz * Tc * Hn;        // [B, H]
  double* v2s  = v1s + (size_t)Bsz * Hn;             // [B, C]
  double* accs = v2s + (size_t)Bsz * Cn;             // [B, C]
  const size_t hcBytes = (size_t)Bsz * Tc * Hn * sizeof(double);

  cvt_w1<<<dim3((Dn * Hn) / (256 * 4)), dim3(256), 0, stream>>>(W1, W1d);

  for (int t0 = 0; t0 < Tn; t0 += Tc) {
    const int rows = Bsz * Tc;
    hipMemsetAsync(Hc, 0, hcBytes, stream);          // atomic accumulation base
    gemm_mfma_f64<<<dim3((rows / TILE_M) * KSPL), dim3(256), 0, stream>>>(
        X, W1d, Hc, t0, Tc);
    snn_scan_f64<<<dim3(Bsz), dim3(64), 0, stream>>>(Hc, b1, W2, b2,
                                                     v1s, v2s, accs, out, t0, Tc);
  }
}